// Round 4
// baseline (672.478 us; speedup 1.0000x reference)
//
#include <hip/hip_runtime.h>

#define NNODES 50000
#define NEDGES 800000
#define HD 128
#define NG 512
#define BN_EPS 1e-5f

typedef short bf16x8 __attribute__((ext_vector_type(8)));
typedef float floatx4 __attribute__((ext_vector_type(4)));

union U16 { uint4 u; bf16x8 h; };

__device__ __forceinline__ ushort f2bf(float f) {
    unsigned u = __float_as_uint(f);
    return (ushort)((u + 0x7fffu + ((u >> 16) & 1u)) >> 16);
}
__device__ __forceinline__ void unpack8(const uint4& u, float* f) {
    const unsigned* w = (const unsigned*)&u;
#pragma unroll
    for (int i = 0; i < 4; ++i) {
        f[2 * i]     = __uint_as_float(w[i] << 16);
        f[2 * i + 1] = __uint_as_float(w[i] & 0xffff0000u);
    }
}
__device__ __forceinline__ uint4 pack8(const float* f) {
    uint4 o;
    unsigned* w = (unsigned*)&o;
#pragma unroll
    for (int i = 0; i < 4; ++i)
        w[i] = (unsigned)f2bf(f[2 * i]) | ((unsigned)f2bf(f[2 * i + 1]) << 16);
    return o;
}

// ---------------- CSR build ----------------

__global__ void hist_kernel(const int* __restrict__ dst, int* __restrict__ cnt, int n) {
    int i = blockIdx.x * 256 + threadIdx.x;
    if (i < n) atomicAdd(&cnt[dst[i]], 1);
}

__global__ void scan1_kernel(const int* __restrict__ cnt, int* __restrict__ incl,
                             int* __restrict__ bsum, int n) {
    __shared__ int s[1024];
    int i = blockIdx.x * 1024 + threadIdx.x;
    int v = (i < n) ? cnt[i] : 0;
    s[threadIdx.x] = v;
    __syncthreads();
    for (int off = 1; off < 1024; off <<= 1) {
        int add = (threadIdx.x >= off) ? s[threadIdx.x - off] : 0;
        __syncthreads();
        s[threadIdx.x] += add;
        __syncthreads();
    }
    if (i < n) incl[i] = s[threadIdx.x];
    if (threadIdx.x == 1023) bsum[blockIdx.x] = s[1023];
}

__global__ void scan2_kernel(const int* __restrict__ bsum, int* __restrict__ boffs, int nb) {
    __shared__ int s[64];
    int v = (threadIdx.x < nb) ? bsum[threadIdx.x] : 0;
    s[threadIdx.x] = v;
    __syncthreads();
    for (int off = 1; off < 64; off <<= 1) {
        int add = (threadIdx.x >= off) ? s[threadIdx.x - off] : 0;
        __syncthreads();
        s[threadIdx.x] += add;
        __syncthreads();
    }
    if (threadIdx.x < nb) boffs[threadIdx.x] = s[threadIdx.x] - v;  // exclusive
}

__global__ void scan3_kernel(const int* __restrict__ incl, const int* __restrict__ boffs,
                             int* __restrict__ rowp, int n) {
    int i = blockIdx.x * 256 + threadIdx.x;
    if (i < n) rowp[i + 1] = incl[i] + boffs[i >> 10];
    if (i == 0) rowp[0] = 0;
}

__global__ void build_kernel(const int* __restrict__ src, const int* __restrict__ dst,
                             const int* __restrict__ rowp, int* __restrict__ fill,
                             int* __restrict__ colv, int n) {
    int i = blockIdx.x * 256 + threadIdx.x;
    if (i < n) {
        int d = dst[i];
        int pos = rowp[d] + atomicAdd(&fill[d], 1);
        colv[pos] = src[i];
    }
}

// ---------------- fp32 -> bf16 convert ----------------

__global__ void cvt_kernel(const float* __restrict__ x, ushort* __restrict__ xb, int n4) {
    int i = blockIdx.x * 256 + threadIdx.x;
    if (i < n4) {
        float4 v = ((const float4*)x)[i];
        ushort4 o;
        o.x = f2bf(v.x); o.y = f2bf(v.y); o.z = f2bf(v.z); o.w = f2bf(v.w);
        ((ushort4*)xb)[i] = o;
    }
}

// ---------------- pack weights into MFMA B-fragment order (bf16) ----------------
// B-frag for mfma_f32_16x16x32_bf16: lane reads B[k=quad*8+j][n=l16] for its (ct,kc).
// Wf flat index: ((ct*4+kc)*64 + lane)*8 + j

struct WP6 { const float* w[6]; };

__global__ void wfrag_kernel(WP6 p, ushort* __restrict__ wf) {
    const float* W = p.w[blockIdx.x];
    ushort* o = wf + (size_t)blockIdx.x * 16384;
    for (int i = threadIdx.x; i < 16384; i += 256) {
        int j = i & 7, lane = (i >> 3) & 63, kc = (i >> 9) & 3, ct = i >> 11;
        int k = kc * 32 + (lane >> 4) * 8 + j;
        int n = ct * 16 + (lane & 15);
        o[i] = f2bf(W[k * HD + n]);
    }
}

// ---------------- aggregation (bf16 rows, fp32 accumulate) ----------------

__global__ __launch_bounds__(256) void aggregate_kernel(
    const ushort* __restrict__ h, const int* __restrict__ rowp,
    const int* __restrict__ colv, ushort* __restrict__ outv, int n) {
    int node = blockIdx.x * 16 + (threadIdx.x >> 4);
    int l = threadIdx.x & 15;  // 16 lanes/node, 16B each
    if (node >= n) return;
    int beg = rowp[node], end = rowp[node + 1];
    const uint4* hp = (const uint4*)h;
    float a[8];
    uint4 sv = hp[(size_t)node * 16 + l];
    unpack8(sv, a);
    for (int j = beg; j < end; ++j) {
        uint4 v = hp[(size_t)colv[j] * 16 + l];
        float b[8];
        unpack8(v, b);
#pragma unroll
        for (int i = 0; i < 8; ++i) a[i] += b[i];
    }
    ((uint4*)outv)[(size_t)node * 16 + l] = pack8(a);
}

// ---------------- MFMA GEMM: [N,128](bf16) @ [128,128](bf16 frags) + bias ----------
// Block = 512 threads (8 waves) covering 4 row-tiles (64 rows) x 128 cols.
// Wave w owns col-pair cp=(w&3) (cols cp*32..cp*32+31, ct = 2cp,2cp+1) and
// row-tiles tile0+ (w>>2) + 2i, i=0..1. B-frags held in registers (8 uint4),
// A streamed from global with one-tile-ahead prefetch. No LDS, no barriers.

template <bool STATS, bool PRE_BN, bool READOUT>
__global__ __launch_bounds__(512) void mfma_gemm_kernel(
    const ushort* __restrict__ A, const ushort* __restrict__ Wf,
    const float* __restrict__ bias, ushort* __restrict__ out,
    const float* __restrict__ scale, const float* __restrict__ shift,
    float* __restrict__ ssum, float* __restrict__ ssq,
    const int* __restrict__ gptr, float* __restrict__ gout, int nrows) {
    const int t = threadIdx.x;
    const int wave = t >> 6, lane = t & 63;
    const int quad = lane >> 4, l16 = lane & 15;
    const int cp = wave & 3;
    const int rslot = wave >> 2;

    const uint4* Wf4 = (const uint4*)Wf;
    uint4 bfr[2][4];
#pragma unroll
    for (int ctl = 0; ctl < 2; ++ctl)
#pragma unroll
        for (int kc = 0; kc < 4; ++kc)
            bfr[ctl][kc] = Wf4[((cp * 2 + ctl) * 4 + kc) * 64 + lane];

    float bia[2];
#pragma unroll
    for (int ctl = 0; ctl < 2; ++ctl) bia[ctl] = bias[(cp * 2 + ctl) * 16 + l16];

    float s_acc[2] = {0.f, 0.f}, q_acc[2] = {0.f, 0.f};

    const int tile0 = blockIdx.x * 4 + rslot;
    floatx4 zf = {0.f, 0.f, 0.f, 0.f};

    uint4 a_cur[4];
    {
        int rowA = tile0 * 16 + l16;
        bool ok = rowA < nrows;
        const ushort* ap = A + (size_t)rowA * HD + quad * 8;
#pragma unroll
        for (int kc = 0; kc < 4; ++kc)
            a_cur[kc] = ok ? *(const uint4*)(ap + kc * 32) : make_uint4(0, 0, 0, 0);
    }

#pragma unroll
    for (int i = 0; i < 2; ++i) {
        const int tile = tile0 + 2 * i;
        uint4 a_nxt[4];
        if (i == 0) {
            int rowA = (tile + 2) * 16 + l16;
            bool ok = rowA < nrows;
            const ushort* ap = A + (size_t)rowA * HD + quad * 8;
#pragma unroll
            for (int kc = 0; kc < 4; ++kc)
                a_nxt[kc] = ok ? *(const uint4*)(ap + kc * 32) : make_uint4(0, 0, 0, 0);
        }

        if (tile * 16 < nrows) {
            floatx4 acc[2] = {zf, zf};
#pragma unroll
            for (int kc = 0; kc < 4; ++kc) {
                U16 au;
                au.u = a_cur[kc];
                if (PRE_BN) {
                    float f[8];
                    unpack8(au.u, f);
                    int kb = kc * 32 + quad * 8;
                    float4 s0 = ((const float4*)(scale + kb))[0];
                    float4 s1 = ((const float4*)(scale + kb))[1];
                    float4 h0 = ((const float4*)(shift + kb))[0];
                    float4 h1 = ((const float4*)(shift + kb))[1];
                    f[0] = fmaxf(fmaf(f[0], s0.x, h0.x), 0.f);
                    f[1] = fmaxf(fmaf(f[1], s0.y, h0.y), 0.f);
                    f[2] = fmaxf(fmaf(f[2], s0.z, h0.z), 0.f);
                    f[3] = fmaxf(fmaf(f[3], s0.w, h0.w), 0.f);
                    f[4] = fmaxf(fmaf(f[4], s1.x, h1.x), 0.f);
                    f[5] = fmaxf(fmaf(f[5], s1.y, h1.y), 0.f);
                    f[6] = fmaxf(fmaf(f[6], s1.z, h1.z), 0.f);
                    f[7] = fmaxf(fmaf(f[7], s1.w, h1.w), 0.f);
                    au.u = pack8(f);
                }
                U16 b0, b1;
                b0.u = bfr[0][kc];
                b1.u = bfr[1][kc];
                acc[0] = __builtin_amdgcn_mfma_f32_16x16x32_bf16(au.h, b0.h, acc[0], 0, 0, 0);
                acc[1] = __builtin_amdgcn_mfma_f32_16x16x32_bf16(au.h, b1.h, acc[1], 0, 0, 0);
            }

            // C/D layout: col = ct*16 + l16, row = tile*16 + quad*4 + reg
            const int r_base = tile * 16 + quad * 4;
            if (READOUT) {
                int segr[4] = {-1, -1, -1, -1};
                {
                    int lo = 0, hi = NG - 1;
                    while (lo < hi) {
                        int mid = (lo + hi) >> 1;
                        if (r_base >= gptr[mid + 1]) lo = mid + 1; else hi = mid;
                    }
                    int sg = lo;
#pragma unroll
                    for (int reg = 0; reg < 4; ++reg) {
                        int rw = r_base + reg;
                        if (rw < nrows) {
                            while (rw >= gptr[sg + 1]) ++sg;
                            segr[reg] = sg;
                        }
                    }
                }
#pragma unroll
                for (int ctl = 0; ctl < 2; ++ctl) {
                    int col = (cp * 2 + ctl) * 16 + l16;
                    float run = 0.f;
                    int cur = segr[0];
#pragma unroll
                    for (int reg = 0; reg < 4; ++reg) {
                        if (segr[reg] != cur) {
                            if (cur >= 0 && run != 0.f) atomicAdd(&gout[cur * HD + col], run);
                            run = 0.f;
                            cur = segr[reg];
                        }
                        if (cur >= 0) run += fmaxf(acc[ctl][reg] + bia[ctl], 0.f);
                    }
                    if (cur >= 0 && run != 0.f) atomicAdd(&gout[cur * HD + col], run);
                }
            } else {
#pragma unroll
                for (int ctl = 0; ctl < 2; ++ctl) {
                    int col = (cp * 2 + ctl) * 16 + l16;
#pragma unroll
                    for (int reg = 0; reg < 4; ++reg) {
                        int rw = r_base + reg;
                        if (rw < nrows) {
                            float v = acc[ctl][reg] + bia[ctl];
                            if (!STATS) v = fmaxf(v, 0.f);  // GEMM-B: relu; GEMM-A: raw
                            out[(size_t)rw * HD + col] = f2bf(v);
                            if (STATS) { s_acc[ctl] += v; q_acc[ctl] += v * v; }
                        }
                    }
                }
            }
        }
#pragma unroll
        for (int kc = 0; kc < 4; ++kc) a_cur[kc] = a_nxt[kc];
    }

    if (STATS) {
#pragma unroll
        for (int ctl = 0; ctl < 2; ++ctl) {
            float s = s_acc[ctl], q = q_acc[ctl];
            s += __shfl_xor(s, 16); s += __shfl_xor(s, 32);
            q += __shfl_xor(q, 16); q += __shfl_xor(q, 32);
            if (quad == 0) {
                int col = (cp * 2 + ctl) * 16 + l16;
                atomicAdd(&ssum[col], s);
                atomicAdd(&ssq[col], q);
            }
        }
    }
}

__global__ void finalize_stats_kernel(const float* __restrict__ s, const float* __restrict__ q,
                                      const float* __restrict__ gamma, const float* __restrict__ beta,
                                      float* __restrict__ scale, float* __restrict__ shift, int n) {
    int c = threadIdx.x;
    float mean = s[c] / (float)n;
    float var = q[c] / (float)n - mean * mean;
    float rstd = rsqrtf(var + BN_EPS);
    float sc = gamma[c] * rstd;
    scale[c] = sc;
    shift[c] = beta[c] - mean * sc;
}

// ---------------- launch ----------------

extern "C" void kernel_launch(void* const* d_in, const int* in_sizes, int n_in,
                              void* d_out, int out_size, void* d_ws, size_t ws_size,
                              hipStream_t stream) {
    const float* x = (const float*)d_in[0];
    const int* esrc = (const int*)d_in[1];
    const int* edst = (const int*)d_in[2];
    const int* gptr = (const int*)d_in[3];
    const float* wA[3] = {(const float*)d_in[4], (const float*)d_in[10], (const float*)d_in[16]};
    const float* bA[3] = {(const float*)d_in[5], (const float*)d_in[11], (const float*)d_in[17]};
    const float* gm[3] = {(const float*)d_in[6], (const float*)d_in[12], (const float*)d_in[18]};
    const float* bt[3] = {(const float*)d_in[7], (const float*)d_in[13], (const float*)d_in[19]};
    const float* wB[3] = {(const float*)d_in[8], (const float*)d_in[14], (const float*)d_in[20]};
    const float* bB[3] = {(const float*)d_in[9], (const float*)d_in[15], (const float*)d_in[21]};

    char* w = (char*)d_ws;
    ushort* xb   = (ushort*)w; w += (size_t)NNODES * HD * 2;  // 12.8 MB
    ushort* tmpb = (ushort*)w; w += (size_t)NNODES * HD * 2;
    ushort* zbb  = (ushort*)w; w += (size_t)NNODES * HD * 2;
    ushort* hbb  = (ushort*)w; w += (size_t)NNODES * HD * 2;
    ushort* wf   = (ushort*)w; w += (size_t)6 * 16384 * 2;    // 192 KB
    int* colv  = (int*)w;   w += (size_t)NEDGES * 4;
    int* incl  = (int*)w;   w += (size_t)NNODES * 4;
    int* rowp  = (int*)w;   w += ((size_t)(NNODES + 1) * 4 + 15) & ~(size_t)15;
    int* bsum  = (int*)w;   w += 64 * 4;
    int* boffs = (int*)w;   w += 64 * 4;
    // ---- zero region ----
    char* zero_base = w;
    int* cnt   = (int*)w;   w += (size_t)NNODES * 4;
    int* fill  = (int*)w;   w += (size_t)NNODES * 4;
    float* ssum   = (float*)w; w += 3 * 128 * 4;
    float* ssq    = (float*)w; w += 3 * 128 * 4;
    float* scaleb = (float*)w; w += 128 * 4;
    float* shiftb = (float*)w; w += 128 * 4;
    size_t zero_bytes = (size_t)(w - zero_base);

    hipMemsetAsync(zero_base, 0, zero_bytes, stream);
    hipMemsetAsync(d_out, 0, (size_t)NG * HD * 4, stream);

    // CSR by destination
    hist_kernel<<<(NEDGES + 255) / 256, 256, 0, stream>>>(edst, cnt, NEDGES);
    int nsb = (NNODES + 1023) / 1024;  // 49
    scan1_kernel<<<nsb, 1024, 0, stream>>>(cnt, incl, bsum, NNODES);
    scan2_kernel<<<1, 64, 0, stream>>>(bsum, boffs, nsb);
    scan3_kernel<<<(NNODES + 255) / 256, 256, 0, stream>>>(incl, boffs, rowp, NNODES);
    build_kernel<<<(NEDGES + 255) / 256, 256, 0, stream>>>(esrc, edst, rowp, fill, colv, NEDGES);

    // bf16 conversions
    cvt_kernel<<<(NNODES * HD / 4 + 255) / 256, 256, 0, stream>>>(x, xb, NNODES * HD / 4);
    WP6 wp;
    wp.w[0] = wA[0]; wp.w[1] = wB[0]; wp.w[2] = wA[1];
    wp.w[3] = wB[1]; wp.w[4] = wA[2]; wp.w[5] = wB[2];
    wfrag_kernel<<<6, 256, 0, stream>>>(wp, wf);

    const int gemm_grid = (NNODES / 16 + 4) / 4;  // 782 blocks x 4 tiles
    const ushort* hin = xb;
    for (int l = 0; l < 3; ++l) {
        aggregate_kernel<<<(NNODES + 15) / 16, 256, 0, stream>>>(hin, rowp, colv, tmpb, NNODES);
        mfma_gemm_kernel<true, false, false><<<gemm_grid, 512, 0, stream>>>(
            tmpb, wf + (size_t)(2 * l) * 16384, bA[l], zbb, nullptr, nullptr,
            ssum + l * 128, ssq + l * 128, nullptr, nullptr, NNODES);
        finalize_stats_kernel<<<1, 128, 0, stream>>>(ssum + l * 128, ssq + l * 128,
                                                     gm[l], bt[l], scaleb, shiftb, NNODES);
        if (l < 2) {
            mfma_gemm_kernel<false, true, false><<<gemm_grid, 512, 0, stream>>>(
                zbb, wf + (size_t)(2 * l + 1) * 16384, bB[l], hbb, scaleb, shiftb,
                nullptr, nullptr, nullptr, nullptr, NNODES);
        } else {
            mfma_gemm_kernel<false, true, true><<<gemm_grid, 512, 0, stream>>>(
                zbb, wf + (size_t)(2 * l + 1) * 16384, bB[l], nullptr, scaleb, shiftb,
                nullptr, nullptr, gptr, (float*)d_out, NNODES);
        }
        hin = hbb;
    }
}

// Round 5
// 509.431 us; speedup vs baseline: 1.3201x; 1.3201x over previous
//
#include <hip/hip_runtime.h>

#define NNODES 50000
#define NEDGES 800000
#define HD 128
#define NG 512
#define BN_EPS 1e-5f

typedef short bf16x8 __attribute__((ext_vector_type(8)));
typedef float floatx4 __attribute__((ext_vector_type(4)));

union U16 { uint4 u; bf16x8 h; };

__device__ __forceinline__ ushort f2bf(float f) {
    unsigned u = __float_as_uint(f);
    return (ushort)((u + 0x7fffu + ((u >> 16) & 1u)) >> 16);
}
__device__ __forceinline__ void unpack8(const uint4& u, float* f) {
    const unsigned* w = (const unsigned*)&u;
#pragma unroll
    for (int i = 0; i < 4; ++i) {
        f[2 * i]     = __uint_as_float(w[i] << 16);
        f[2 * i + 1] = __uint_as_float(w[i] & 0xffff0000u);
    }
}
__device__ __forceinline__ uint4 pack8(const float* f) {
    uint4 o;
    unsigned* w = (unsigned*)&o;
#pragma unroll
    for (int i = 0; i < 4; ++i)
        w[i] = (unsigned)f2bf(f[2 * i]) | ((unsigned)f2bf(f[2 * i + 1]) << 16);
    return o;
}

// ---------------- CSR build ----------------

__global__ void hist_kernel(const int* __restrict__ dst, int* __restrict__ cnt, int n) {
    int i = blockIdx.x * 256 + threadIdx.x;
    if (i < n) atomicAdd(&cnt[dst[i]], 1);
}

__global__ void scan1_kernel(const int* __restrict__ cnt, int* __restrict__ incl,
                             int* __restrict__ bsum, int n) {
    __shared__ int s[1024];
    int i = blockIdx.x * 1024 + threadIdx.x;
    int v = (i < n) ? cnt[i] : 0;
    s[threadIdx.x] = v;
    __syncthreads();
    for (int off = 1; off < 1024; off <<= 1) {
        int add = (threadIdx.x >= off) ? s[threadIdx.x - off] : 0;
        __syncthreads();
        s[threadIdx.x] += add;
        __syncthreads();
    }
    if (i < n) incl[i] = s[threadIdx.x];
    if (threadIdx.x == 1023) bsum[blockIdx.x] = s[1023];
}

__global__ void scan2_kernel(const int* __restrict__ bsum, int* __restrict__ boffs, int nb) {
    __shared__ int s[64];
    int v = (threadIdx.x < nb) ? bsum[threadIdx.x] : 0;
    s[threadIdx.x] = v;
    __syncthreads();
    for (int off = 1; off < 64; off <<= 1) {
        int add = (threadIdx.x >= off) ? s[threadIdx.x - off] : 0;
        __syncthreads();
        s[threadIdx.x] += add;
        __syncthreads();
    }
    if (threadIdx.x < nb) boffs[threadIdx.x] = s[threadIdx.x] - v;  // exclusive
}

__global__ void scan3_kernel(const int* __restrict__ incl, const int* __restrict__ boffs,
                             int* __restrict__ rowp, int n) {
    int i = blockIdx.x * 256 + threadIdx.x;
    if (i < n) rowp[i + 1] = incl[i] + boffs[i >> 10];
    if (i == 0) rowp[0] = 0;
}

__global__ void build_kernel(const int* __restrict__ src, const int* __restrict__ dst,
                             const int* __restrict__ rowp, int* __restrict__ fill,
                             int* __restrict__ colv, int n) {
    int i = blockIdx.x * 256 + threadIdx.x;
    if (i < n) {
        int d = dst[i];
        int pos = rowp[d] + atomicAdd(&fill[d], 1);
        colv[pos] = src[i];
    }
}

// ---------------- fp32 -> bf16 convert ----------------

__global__ void cvt_kernel(const float* __restrict__ x, ushort* __restrict__ xb, int n4) {
    int i = blockIdx.x * 256 + threadIdx.x;
    if (i < n4) {
        float4 v = ((const float4*)x)[i];
        ushort4 o;
        o.x = f2bf(v.x); o.y = f2bf(v.y); o.z = f2bf(v.z); o.w = f2bf(v.w);
        ((ushort4*)xb)[i] = o;
    }
}

// ---------------- pack weights into MFMA B-fragment order (bf16) ----------------
// B-frag for mfma_f32_16x16x32_bf16: lane reads B[k=quad*8+j][n=l16] for its (ct,kc).
// Wf flat index: ((ct*4+kc)*64 + lane)*8 + j

struct WP6 { const float* w[6]; };

__global__ void wfrag_kernel(WP6 p, ushort* __restrict__ wf) {
    const float* W = p.w[blockIdx.x];
    ushort* o = wf + (size_t)blockIdx.x * 16384;
    for (int i = threadIdx.x; i < 16384; i += 256) {
        int j = i & 7, lane = (i >> 3) & 63, kc = (i >> 9) & 3, ct = i >> 11;
        int k = kc * 32 + (lane >> 4) * 8 + j;
        int n = ct * 16 + (lane & 15);
        o[i] = f2bf(W[k * HD + n]);
    }
}

// ---------------- aggregation (bf16 rows, fp32 accumulate) ----------------

__global__ __launch_bounds__(256) void aggregate_kernel(
    const ushort* __restrict__ h, const int* __restrict__ rowp,
    const int* __restrict__ colv, ushort* __restrict__ outv, int n) {
    int node = blockIdx.x * 16 + (threadIdx.x >> 4);
    int l = threadIdx.x & 15;  // 16 lanes/node, 16B each
    if (node >= n) return;
    int beg = rowp[node], end = rowp[node + 1];
    const uint4* hp = (const uint4*)h;
    float a[8];
    uint4 sv = hp[(size_t)node * 16 + l];
    unpack8(sv, a);
    for (int j = beg; j < end; ++j) {
        uint4 v = hp[(size_t)colv[j] * 16 + l];
        float b[8];
        unpack8(v, b);
#pragma unroll
        for (int i = 0; i < 8; ++i) a[i] += b[i];
    }
    ((uint4*)outv)[(size_t)node * 16 + l] = pack8(a);
}

// ---------------- MFMA GEMM: [N,128](bf16) @ [128,128](bf16 frags) + bias ----------
// Block = 256 threads (4 waves), 64 rows x 128 cols. B-fragments (32KB) staged
// cooperatively into LDS once per block; per-MFMA B access = ds_read_b128
// (conflict-free, lgkmcnt-batched). A direct from global, issued before barrier.

template <bool STATS, bool PRE_BN, bool READOUT>
__global__ __launch_bounds__(256, 4) void mfma_gemm_kernel(
    const ushort* __restrict__ A, const ushort* __restrict__ Wf,
    const float* __restrict__ bias, ushort* __restrict__ out,
    const float* __restrict__ scale, const float* __restrict__ shift,
    float* __restrict__ ssum, float* __restrict__ ssq,
    const int* __restrict__ gptr, float* __restrict__ gout, int nrows) {
    __shared__ ushort bs[16384];      // 32 KB B-fragments
    __shared__ float reds[4][HD];
    __shared__ float redq[4][HD];
    const int t = threadIdx.x;
    const int wave = t >> 6, lane = t & 63;
    const int quad = lane >> 4, l16 = lane & 15;
    const int rowA = blockIdx.x * 64 + wave * 16 + l16;  // A-operand row for this lane

    // stage B into LDS: 2048 uint4, 8 per thread (loads issued back-to-back)
    {
        const uint4* g = (const uint4*)Wf;
        uint4 v[8];
#pragma unroll
        for (int i = 0; i < 8; ++i) v[i] = g[i * 256 + t];
        uint4* s = (uint4*)bs;
#pragma unroll
        for (int i = 0; i < 8; ++i) s[i * 256 + t] = v[i];
    }

    // A loads: issue before the barrier so latency overlaps staging
    uint4 a_cur[4];
    {
        bool ok = rowA < nrows;
        const ushort* ap = A + (size_t)rowA * HD + quad * 8;
#pragma unroll
        for (int kc = 0; kc < 4; ++kc)
            a_cur[kc] = ok ? *(const uint4*)(ap + kc * 32) : make_uint4(0, 0, 0, 0);
    }

    __syncthreads();

    floatx4 zf = {0.f, 0.f, 0.f, 0.f};
    floatx4 acc[8];
#pragma unroll
    for (int i = 0; i < 8; ++i) acc[i] = zf;

    const uint4* B4 = (const uint4*)bs;

#pragma unroll
    for (int kc = 0; kc < 4; ++kc) {
        U16 au;
        au.u = a_cur[kc];
        if (PRE_BN) {
            float f[8];
            unpack8(au.u, f);
            int kb = kc * 32 + quad * 8;
            float4 s0 = ((const float4*)(scale + kb))[0];
            float4 s1 = ((const float4*)(scale + kb))[1];
            float4 h0 = ((const float4*)(shift + kb))[0];
            float4 h1 = ((const float4*)(shift + kb))[1];
            f[0] = fmaxf(fmaf(f[0], s0.x, h0.x), 0.f);
            f[1] = fmaxf(fmaf(f[1], s0.y, h0.y), 0.f);
            f[2] = fmaxf(fmaf(f[2], s0.z, h0.z), 0.f);
            f[3] = fmaxf(fmaf(f[3], s0.w, h0.w), 0.f);
            f[4] = fmaxf(fmaf(f[4], s1.x, h1.x), 0.f);
            f[5] = fmaxf(fmaf(f[5], s1.y, h1.y), 0.f);
            f[6] = fmaxf(fmaf(f[6], s1.z, h1.z), 0.f);
            f[7] = fmaxf(fmaf(f[7], s1.w, h1.w), 0.f);
            au.u = pack8(f);
        }
#pragma unroll
        for (int ct = 0; ct < 8; ++ct) {
            U16 bu;
            bu.u = B4[(ct * 4 + kc) * 64 + lane];
            acc[ct] = __builtin_amdgcn_mfma_f32_16x16x32_bf16(au.h, bu.h, acc[ct], 0, 0, 0);
        }
    }

    // C/D layout: col = ct*16 + l16, row = blockIdx*64 + wave*16 + quad*4 + reg
    const int r_base = blockIdx.x * 64 + wave * 16 + quad * 4;

    if (READOUT) {
        int segr[4] = {-1, -1, -1, -1};
        if (r_base < nrows) {
            int lo = 0, hi = NG - 1;
            while (lo < hi) {
                int mid = (lo + hi) >> 1;
                if (r_base >= gptr[mid + 1]) lo = mid + 1; else hi = mid;
            }
            int sg = lo;
#pragma unroll
            for (int reg = 0; reg < 4; ++reg) {
                int rw = r_base + reg;
                if (rw < nrows) {
                    while (rw >= gptr[sg + 1]) ++sg;
                    segr[reg] = sg;
                }
            }
        }
#pragma unroll
        for (int ct = 0; ct < 8; ++ct) {
            int col = ct * 16 + l16;
            float b = bias[col];
            float run = 0.f;
            int cur = segr[0];
#pragma unroll
            for (int reg = 0; reg < 4; ++reg) {
                if (segr[reg] != cur) {
                    if (cur >= 0 && run != 0.f) atomicAdd(&gout[cur * HD + col], run);
                    run = 0.f;
                    cur = segr[reg];
                }
                if (cur >= 0) run += fmaxf(acc[ct][reg] + b, 0.f);
            }
            if (cur >= 0 && run != 0.f) atomicAdd(&gout[cur * HD + col], run);
        }
    } else {
#pragma unroll
        for (int ct = 0; ct < 8; ++ct) {
            int col = ct * 16 + l16;
            float b = bias[col];
            float s = 0.f, q = 0.f;
#pragma unroll
            for (int reg = 0; reg < 4; ++reg) {
                int rw = r_base + reg;
                if (rw < nrows) {
                    float v = acc[ct][reg] + b;
                    if (!STATS) v = fmaxf(v, 0.f);  // GEMM-B: relu; GEMM-A: raw pre-BN
                    out[(size_t)rw * HD + col] = f2bf(v);
                    if (STATS) { s += v; q += v * v; }
                }
            }
            if (STATS) {
                s += __shfl_xor(s, 16); s += __shfl_xor(s, 32);
                q += __shfl_xor(q, 16); q += __shfl_xor(q, 32);
                if (quad == 0) { reds[wave][col] = s; redq[wave][col] = q; }
            }
        }
        if (STATS) {
            __syncthreads();
            if (t < HD) {
                atomicAdd(&ssum[t], reds[0][t] + reds[1][t] + reds[2][t] + reds[3][t]);
            } else {
                int c = t - HD;
                atomicAdd(&ssq[c], redq[0][c] + redq[1][c] + redq[2][c] + redq[3][c]);
            }
        }
    }
}

__global__ void finalize_stats_kernel(const float* __restrict__ s, const float* __restrict__ q,
                                      const float* __restrict__ gamma, const float* __restrict__ beta,
                                      float* __restrict__ scale, float* __restrict__ shift, int n) {
    int c = threadIdx.x;
    float mean = s[c] / (float)n;
    float var = q[c] / (float)n - mean * mean;
    float rstd = rsqrtf(var + BN_EPS);
    float sc = gamma[c] * rstd;
    scale[c] = sc;
    shift[c] = beta[c] - mean * sc;
}

// ---------------- launch ----------------

extern "C" void kernel_launch(void* const* d_in, const int* in_sizes, int n_in,
                              void* d_out, int out_size, void* d_ws, size_t ws_size,
                              hipStream_t stream) {
    const float* x = (const float*)d_in[0];
    const int* esrc = (const int*)d_in[1];
    const int* edst = (const int*)d_in[2];
    const int* gptr = (const int*)d_in[3];
    const float* wA[3] = {(const float*)d_in[4], (const float*)d_in[10], (const float*)d_in[16]};
    const float* bA[3] = {(const float*)d_in[5], (const float*)d_in[11], (const float*)d_in[17]};
    const float* gm[3] = {(const float*)d_in[6], (const float*)d_in[12], (const float*)d_in[18]};
    const float* bt[3] = {(const float*)d_in[7], (const float*)d_in[13], (const float*)d_in[19]};
    const float* wB[3] = {(const float*)d_in[8], (const float*)d_in[14], (const float*)d_in[20]};
    const float* bB[3] = {(const float*)d_in[9], (const float*)d_in[15], (const float*)d_in[21]};

    char* w = (char*)d_ws;
    ushort* xb   = (ushort*)w; w += (size_t)NNODES * HD * 2;  // 12.8 MB
    ushort* tmpb = (ushort*)w; w += (size_t)NNODES * HD * 2;
    ushort* zbb  = (ushort*)w; w += (size_t)NNODES * HD * 2;
    ushort* hbb  = (ushort*)w; w += (size_t)NNODES * HD * 2;
    ushort* wf   = (ushort*)w; w += (size_t)6 * 16384 * 2;    // 192 KB
    int* colv  = (int*)w;   w += (size_t)NEDGES * 4;
    int* incl  = (int*)w;   w += (size_t)NNODES * 4;
    int* rowp  = (int*)w;   w += ((size_t)(NNODES + 1) * 4 + 15) & ~(size_t)15;
    int* bsum  = (int*)w;   w += 64 * 4;
    int* boffs = (int*)w;   w += 64 * 4;
    // ---- zero region ----
    char* zero_base = w;
    int* cnt   = (int*)w;   w += (size_t)NNODES * 4;
    int* fill  = (int*)w;   w += (size_t)NNODES * 4;
    float* ssum   = (float*)w; w += 3 * 128 * 4;
    float* ssq    = (float*)w; w += 3 * 128 * 4;
    float* scaleb = (float*)w; w += 128 * 4;
    float* shiftb = (float*)w; w += 128 * 4;
    size_t zero_bytes = (size_t)(w - zero_base);

    hipMemsetAsync(zero_base, 0, zero_bytes, stream);
    hipMemsetAsync(d_out, 0, (size_t)NG * HD * 4, stream);

    // CSR by destination
    hist_kernel<<<(NEDGES + 255) / 256, 256, 0, stream>>>(edst, cnt, NEDGES);
    int nsb = (NNODES + 1023) / 1024;  // 49
    scan1_kernel<<<nsb, 1024, 0, stream>>>(cnt, incl, bsum, NNODES);
    scan2_kernel<<<1, 64, 0, stream>>>(bsum, boffs, nsb);
    scan3_kernel<<<(NNODES + 255) / 256, 256, 0, stream>>>(incl, boffs, rowp, NNODES);
    build_kernel<<<(NEDGES + 255) / 256, 256, 0, stream>>>(esrc, edst, rowp, fill, colv, NEDGES);

    // bf16 conversions
    cvt_kernel<<<(NNODES * HD / 4 + 255) / 256, 256, 0, stream>>>(x, xb, NNODES * HD / 4);
    WP6 wp;
    wp.w[0] = wA[0]; wp.w[1] = wB[0]; wp.w[2] = wA[1];
    wp.w[3] = wB[1]; wp.w[4] = wA[2]; wp.w[5] = wB[2];
    wfrag_kernel<<<6, 256, 0, stream>>>(wp, wf);

    const int gemm_grid = (NNODES + 63) / 64;  // 782
    const ushort* hin = xb;
    for (int l = 0; l < 3; ++l) {
        aggregate_kernel<<<(NNODES + 15) / 16, 256, 0, stream>>>(hin, rowp, colv, tmpb, NNODES);
        mfma_gemm_kernel<true, false, false><<<gemm_grid, 256, 0, stream>>>(
            tmpb, wf + (size_t)(2 * l) * 16384, bA[l], zbb, nullptr, nullptr,
            ssum + l * 128, ssq + l * 128, nullptr, nullptr, NNODES);
        finalize_stats_kernel<<<1, 128, 0, stream>>>(ssum + l * 128, ssq + l * 128,
                                                     gm[l], bt[l], scaleb, shiftb, NNODES);
        if (l < 2) {
            mfma_gemm_kernel<false, true, false><<<gemm_grid, 256, 0, stream>>>(
                zbb, wf + (size_t)(2 * l + 1) * 16384, bB[l], hbb, scaleb, shiftb,
                nullptr, nullptr, nullptr, nullptr, NNODES);
        } else {
            mfma_gemm_kernel<false, true, true><<<gemm_grid, 256, 0, stream>>>(
                zbb, wf + (size_t)(2 * l + 1) * 16384, bB[l], nullptr, scaleb, shiftb,
                nullptr, nullptr, gptr, (float*)d_out, NNODES);
        }
        hin = hbb;
    }
}

// Round 6
// 505.708 us; speedup vs baseline: 1.3298x; 1.0074x over previous
//
#include <hip/hip_runtime.h>

#define NNODES 50000
#define NEDGES 800000
#define HD 128
#define NG 512
#define BN_EPS 1e-5f

typedef short bf16x8 __attribute__((ext_vector_type(8)));
typedef float floatx4 __attribute__((ext_vector_type(4)));

union U16 { uint4 u; bf16x8 h; };

__device__ __forceinline__ ushort f2bf(float f) {
    unsigned u = __float_as_uint(f);
    return (ushort)((u + 0x7fffu + ((u >> 16) & 1u)) >> 16);
}
__device__ __forceinline__ void unpack8(const uint4& u, float* f) {
    const unsigned* w = (const unsigned*)&u;
#pragma unroll
    for (int i = 0; i < 4; ++i) {
        f[2 * i]     = __uint_as_float(w[i] << 16);
        f[2 * i + 1] = __uint_as_float(w[i] & 0xffff0000u);
    }
}
__device__ __forceinline__ uint4 pack8(const float* f) {
    uint4 o;
    unsigned* w = (unsigned*)&o;
#pragma unroll
    for (int i = 0; i < 4; ++i)
        w[i] = (unsigned)f2bf(f[2 * i]) | ((unsigned)f2bf(f[2 * i + 1]) << 16);
    return o;
}

// ---------------- CSR build ----------------

__global__ void hist_kernel(const int* __restrict__ dst, int* __restrict__ cnt, int n) {
    int i = blockIdx.x * 256 + threadIdx.x;
    if (i < n) atomicAdd(&cnt[dst[i]], 1);
}

__global__ void scan1_kernel(const int* __restrict__ cnt, int* __restrict__ incl,
                             int* __restrict__ bsum, int n) {
    __shared__ int s[1024];
    int i = blockIdx.x * 1024 + threadIdx.x;
    int v = (i < n) ? cnt[i] : 0;
    s[threadIdx.x] = v;
    __syncthreads();
    for (int off = 1; off < 1024; off <<= 1) {
        int add = (threadIdx.x >= off) ? s[threadIdx.x - off] : 0;
        __syncthreads();
        s[threadIdx.x] += add;
        __syncthreads();
    }
    if (i < n) incl[i] = s[threadIdx.x];
    if (threadIdx.x == 1023) bsum[blockIdx.x] = s[1023];
}

__global__ void scan2_kernel(const int* __restrict__ bsum, int* __restrict__ boffs, int nb) {
    __shared__ int s[64];
    int v = (threadIdx.x < nb) ? bsum[threadIdx.x] : 0;
    s[threadIdx.x] = v;
    __syncthreads();
    for (int off = 1; off < 64; off <<= 1) {
        int add = (threadIdx.x >= off) ? s[threadIdx.x - off] : 0;
        __syncthreads();
        s[threadIdx.x] += add;
        __syncthreads();
    }
    if (threadIdx.x < nb) boffs[threadIdx.x] = s[threadIdx.x] - v;  // exclusive
}

__global__ void scan3_kernel(const int* __restrict__ incl, const int* __restrict__ boffs,
                             int* __restrict__ rowp, int n) {
    int i = blockIdx.x * 256 + threadIdx.x;
    if (i < n) rowp[i + 1] = incl[i] + boffs[i >> 10];
    if (i == 0) rowp[0] = 0;
}

__global__ void build_kernel(const int* __restrict__ src, const int* __restrict__ dst,
                             const int* __restrict__ rowp, int* __restrict__ fill,
                             int* __restrict__ colv, int n) {
    int i = blockIdx.x * 256 + threadIdx.x;
    if (i < n) {
        int d = dst[i];
        int pos = rowp[d] + atomicAdd(&fill[d], 1);
        colv[pos] = src[i];
    }
}

// ---------------- pack weights into MFMA B-fragment order (bf16) ----------------
// B-frag for mfma_f32_16x16x32_bf16: lane reads B[k=quad*8+j][n=l16] for its (ct,kc).
// Wf flat index: ((ct*4+kc)*64 + lane)*8 + j

struct WP6 { const float* w[6]; };

__global__ void wfrag_kernel(WP6 p, ushort* __restrict__ wf) {
    const float* W = p.w[blockIdx.x];
    ushort* o = wf + (size_t)blockIdx.x * 16384;
    for (int i = threadIdx.x; i < 16384; i += 256) {
        int j = i & 7, lane = (i >> 3) & 63, kc = (i >> 9) & 3, ct = i >> 11;
        int k = kc * 32 + (lane >> 4) * 8 + j;
        int n = ct * 16 + (lane & 15);
        o[i] = f2bf(W[k * HD + n]);
    }
}

// ---------------- aggregation (fp32 accumulate, bf16 out) ----------------

__global__ __launch_bounds__(256) void aggregate_f32_kernel(
    const float* __restrict__ x, const int* __restrict__ rowp,
    const int* __restrict__ colv, ushort* __restrict__ outv, int n) {
    int node = blockIdx.x * 16 + (threadIdx.x >> 4);
    int l = threadIdx.x & 15;  // 8 floats per lane
    if (node >= n) return;
    int beg = rowp[node], end = rowp[node + 1];
    const float4* hp = (const float4*)x;
    float a[8];
    {
        float4 v0 = hp[(size_t)node * 32 + l * 2];
        float4 v1 = hp[(size_t)node * 32 + l * 2 + 1];
        a[0] = v0.x; a[1] = v0.y; a[2] = v0.z; a[3] = v0.w;
        a[4] = v1.x; a[5] = v1.y; a[6] = v1.z; a[7] = v1.w;
    }
    for (int j = beg; j < end; ++j) {
        size_t s = (size_t)colv[j] * 32 + l * 2;
        float4 v0 = hp[s], v1 = hp[s + 1];
        a[0] += v0.x; a[1] += v0.y; a[2] += v0.z; a[3] += v0.w;
        a[4] += v1.x; a[5] += v1.y; a[6] += v1.z; a[7] += v1.w;
    }
    ((uint4*)outv)[(size_t)node * 16 + l] = pack8(a);
}

__global__ __launch_bounds__(256) void aggregate_kernel(
    const ushort* __restrict__ h, const int* __restrict__ rowp,
    const int* __restrict__ colv, ushort* __restrict__ outv, int n) {
    int node = blockIdx.x * 16 + (threadIdx.x >> 4);
    int l = threadIdx.x & 15;  // 16 lanes/node, 16B each
    if (node >= n) return;
    int beg = rowp[node], end = rowp[node + 1];
    const uint4* hp = (const uint4*)h;
    float a[8];
    uint4 sv = hp[(size_t)node * 16 + l];
    unpack8(sv, a);
    for (int j = beg; j < end; ++j) {
        uint4 v = hp[(size_t)colv[j] * 16 + l];
        float b[8];
        unpack8(v, b);
#pragma unroll
        for (int i = 0; i < 8; ++i) a[i] += b[i];
    }
    ((uint4*)outv)[(size_t)node * 16 + l] = pack8(a);
}

// ---------------- MFMA GEMM: [N,128](bf16) @ [128,128](bf16 frags) + bias ----------
// Block = 256 threads (4 waves), 64 rows x 128 cols. B-fragments (32KB) staged in
// LDS; C tile round-trips through the same LDS for fully-coalesced uint4 stores.
// PRE_BN computes BN scale/shift from raw stats inline (no separate kernel).

template <bool STATS, bool PRE_BN, bool READOUT>
__global__ __launch_bounds__(256, 4) void mfma_gemm_kernel(
    const ushort* __restrict__ A, const ushort* __restrict__ Wf,
    const float* __restrict__ bias, ushort* __restrict__ out,
    const float* __restrict__ gamma, const float* __restrict__ beta,
    float* __restrict__ ssum, float* __restrict__ ssq,
    const int* __restrict__ gptr, float* __restrict__ gout, int nrows) {
    __shared__ ushort bs[16384];      // 32 KB B-fragments, then C tile
    __shared__ float reds[4][HD];
    __shared__ float redq[4][HD];
    __shared__ float sca[HD];
    __shared__ float shf[HD];
    const int t = threadIdx.x;
    const int wave = t >> 6, lane = t & 63;
    const int quad = lane >> 4, l16 = lane & 15;
    const int row0 = blockIdx.x * 64;
    const int rowA = row0 + wave * 16 + l16;  // A-operand row for this lane

    // stage B into LDS: 2048 uint4, 8 per thread (loads issued back-to-back)
    {
        const uint4* g = (const uint4*)Wf;
        uint4 v[8];
#pragma unroll
        for (int i = 0; i < 8; ++i) v[i] = g[i * 256 + t];
        uint4* s = (uint4*)bs;
#pragma unroll
        for (int i = 0; i < 8; ++i) s[i * 256 + t] = v[i];
    }

    // inline BN finalize (stats are complete: stream-ordered after GEMM-A)
    if (PRE_BN && t < HD) {
        float mean = ssum[t] / (float)nrows;
        float var = ssq[t] / (float)nrows - mean * mean;
        float rstd = rsqrtf(var + BN_EPS);
        float sc = gamma[t] * rstd;
        sca[t] = sc;
        shf[t] = beta[t] - mean * sc;
    }

    // A loads: issue before the barrier so latency overlaps staging
    uint4 a_cur[4];
    {
        bool ok = rowA < nrows;
        const ushort* ap = A + (size_t)rowA * HD + quad * 8;
#pragma unroll
        for (int kc = 0; kc < 4; ++kc)
            a_cur[kc] = ok ? *(const uint4*)(ap + kc * 32) : make_uint4(0, 0, 0, 0);
    }

    __syncthreads();

    floatx4 zf = {0.f, 0.f, 0.f, 0.f};
    floatx4 acc[8];
#pragma unroll
    for (int i = 0; i < 8; ++i) acc[i] = zf;

    const uint4* B4 = (const uint4*)bs;

#pragma unroll
    for (int kc = 0; kc < 4; ++kc) {
        U16 au;
        au.u = a_cur[kc];
        if (PRE_BN) {
            float f[8];
            unpack8(au.u, f);
            int kb = kc * 32 + quad * 8;
            float4 s0 = ((const float4*)(sca + kb))[0];
            float4 s1 = ((const float4*)(sca + kb))[1];
            float4 h0 = ((const float4*)(shf + kb))[0];
            float4 h1 = ((const float4*)(shf + kb))[1];
            f[0] = fmaxf(fmaf(f[0], s0.x, h0.x), 0.f);
            f[1] = fmaxf(fmaf(f[1], s0.y, h0.y), 0.f);
            f[2] = fmaxf(fmaf(f[2], s0.z, h0.z), 0.f);
            f[3] = fmaxf(fmaf(f[3], s0.w, h0.w), 0.f);
            f[4] = fmaxf(fmaf(f[4], s1.x, h1.x), 0.f);
            f[5] = fmaxf(fmaf(f[5], s1.y, h1.y), 0.f);
            f[6] = fmaxf(fmaf(f[6], s1.z, h1.z), 0.f);
            f[7] = fmaxf(fmaf(f[7], s1.w, h1.w), 0.f);
            au.u = pack8(f);
        }
#pragma unroll
        for (int ct = 0; ct < 8; ++ct) {
            U16 bu;
            bu.u = B4[(ct * 4 + kc) * 64 + lane];
            acc[ct] = __builtin_amdgcn_mfma_f32_16x16x32_bf16(au.h, bu.h, acc[ct], 0, 0, 0);
        }
    }

    // C/D layout: col = ct*16 + l16, row = row0 + wave*16 + quad*4 + reg
    const int r_base = row0 + wave * 16 + quad * 4;

    if (READOUT) {
        int segr[4] = {-1, -1, -1, -1};
        if (r_base < nrows) {
            int lo = 0, hi = NG - 1;
            while (lo < hi) {
                int mid = (lo + hi) >> 1;
                if (r_base >= gptr[mid + 1]) lo = mid + 1; else hi = mid;
            }
            int sg = lo;
#pragma unroll
            for (int reg = 0; reg < 4; ++reg) {
                int rw = r_base + reg;
                if (rw < nrows) {
                    while (rw >= gptr[sg + 1]) ++sg;
                    segr[reg] = sg;
                }
            }
        }
#pragma unroll
        for (int ct = 0; ct < 8; ++ct) {
            int col = ct * 16 + l16;
            float b = bias[col];
            float run = 0.f;
            int cur = segr[0];
#pragma unroll
            for (int reg = 0; reg < 4; ++reg) {
                if (segr[reg] != cur) {
                    if (cur >= 0 && run != 0.f) atomicAdd(&gout[cur * HD + col], run);
                    run = 0.f;
                    cur = segr[reg];
                }
                if (cur >= 0) run += fmaxf(acc[ct][reg] + b, 0.f);
            }
            if (cur >= 0 && run != 0.f) atomicAdd(&gout[cur * HD + col], run);
        }
    } else {
        __syncthreads();  // all waves done reading B fragments from bs
        const int lrow = wave * 16 + quad * 4;
#pragma unroll
        for (int ct = 0; ct < 8; ++ct) {
            int col = ct * 16 + l16;
            float b = bias[col];
            float s = 0.f, q = 0.f;
#pragma unroll
            for (int reg = 0; reg < 4; ++reg) {
                float v = acc[ct][reg] + b;
                if (!STATS) v = fmaxf(v, 0.f);  // GEMM-B: relu; GEMM-A: raw pre-BN
                bs[(lrow + reg) * HD + col] = f2bf(v);
                if (STATS && (r_base + reg) < nrows) { s += v; q += v * v; }
            }
            if (STATS) {
                s += __shfl_xor(s, 16); s += __shfl_xor(s, 32);
                q += __shfl_xor(q, 16); q += __shfl_xor(q, 32);
                if (quad == 0) { reds[wave][col] = s; redq[wave][col] = q; }
            }
        }
        __syncthreads();  // C tile + stats partials complete
        // coalesced C store: 1024 uint4, 4 consecutive per thread
        const uint4* c4 = (const uint4*)bs;
        uint4* o4 = (uint4*)out;
#pragma unroll
        for (int i = 0; i < 4; ++i) {
            int f = t * 4 + i;
            int row = f >> 4;
            if (row0 + row < nrows) o4[(size_t)(row0 + row) * 16 + (f & 15)] = c4[f];
        }
        if (STATS) {
            if (t < HD) {
                atomicAdd(&ssum[t], reds[0][t] + reds[1][t] + reds[2][t] + reds[3][t]);
            } else {
                int c = t - HD;
                atomicAdd(&ssq[c], redq[0][c] + redq[1][c] + redq[2][c] + redq[3][c]);
            }
        }
    }
}

// ---------------- launch ----------------

extern "C" void kernel_launch(void* const* d_in, const int* in_sizes, int n_in,
                              void* d_out, int out_size, void* d_ws, size_t ws_size,
                              hipStream_t stream) {
    const float* x = (const float*)d_in[0];
    const int* esrc = (const int*)d_in[1];
    const int* edst = (const int*)d_in[2];
    const int* gptr = (const int*)d_in[3];
    const float* wA[3] = {(const float*)d_in[4], (const float*)d_in[10], (const float*)d_in[16]};
    const float* bA[3] = {(const float*)d_in[5], (const float*)d_in[11], (const float*)d_in[17]};
    const float* gm[3] = {(const float*)d_in[6], (const float*)d_in[12], (const float*)d_in[18]};
    const float* bt[3] = {(const float*)d_in[7], (const float*)d_in[13], (const float*)d_in[19]};
    const float* wB[3] = {(const float*)d_in[8], (const float*)d_in[14], (const float*)d_in[20]};
    const float* bB[3] = {(const float*)d_in[9], (const float*)d_in[15], (const float*)d_in[21]};

    char* w = (char*)d_ws;
    ushort* tmpb = (ushort*)w; w += (size_t)NNODES * HD * 2;  // 12.8 MB
    ushort* zbb  = (ushort*)w; w += (size_t)NNODES * HD * 2;
    ushort* hbb  = (ushort*)w; w += (size_t)NNODES * HD * 2;
    ushort* wf   = (ushort*)w; w += (size_t)6 * 16384 * 2;    // 192 KB
    int* colv  = (int*)w;   w += (size_t)NEDGES * 4;
    int* incl  = (int*)w;   w += (size_t)NNODES * 4;
    int* rowp  = (int*)w;   w += ((size_t)(NNODES + 1) * 4 + 15) & ~(size_t)15;
    int* bsum  = (int*)w;   w += 64 * 4;
    int* boffs = (int*)w;   w += 64 * 4;
    // ---- zero region ----
    char* zero_base = w;
    int* cnt   = (int*)w;   w += (size_t)NNODES * 4;
    int* fill  = (int*)w;   w += (size_t)NNODES * 4;
    float* ssum   = (float*)w; w += 3 * 128 * 4;
    float* ssq    = (float*)w; w += 3 * 128 * 4;
    size_t zero_bytes = (size_t)(w - zero_base);

    hipMemsetAsync(zero_base, 0, zero_bytes, stream);
    hipMemsetAsync(d_out, 0, (size_t)NG * HD * 4, stream);

    // CSR by destination
    hist_kernel<<<(NEDGES + 255) / 256, 256, 0, stream>>>(edst, cnt, NEDGES);
    int nsb = (NNODES + 1023) / 1024;  // 49
    scan1_kernel<<<nsb, 1024, 0, stream>>>(cnt, incl, bsum, NNODES);
    scan2_kernel<<<1, 64, 0, stream>>>(bsum, boffs, nsb);
    scan3_kernel<<<(NNODES + 255) / 256, 256, 0, stream>>>(incl, boffs, rowp, NNODES);
    build_kernel<<<(NEDGES + 255) / 256, 256, 0, stream>>>(esrc, edst, rowp, fill, colv, NEDGES);

    WP6 wp;
    wp.w[0] = wA[0]; wp.w[1] = wB[0]; wp.w[2] = wA[1];
    wp.w[3] = wB[1]; wp.w[4] = wA[2]; wp.w[5] = wB[2];
    wfrag_kernel<<<6, 256, 0, stream>>>(wp, wf);

    const int gemm_grid = (NNODES + 63) / 64;  // 782
    const int agg_grid = (NNODES + 15) / 16;   // 3125
    const ushort* hin = hbb;
    for (int l = 0; l < 3; ++l) {
        if (l == 0)
            aggregate_f32_kernel<<<agg_grid, 256, 0, stream>>>(x, rowp, colv, tmpb, NNODES);
        else
            aggregate_kernel<<<agg_grid, 256, 0, stream>>>(hin, rowp, colv, tmpb, NNODES);
        mfma_gemm_kernel<true, false, false><<<gemm_grid, 256, 0, stream>>>(
            tmpb, wf + (size_t)(2 * l) * 16384, bA[l], zbb, nullptr, nullptr,
            ssum + l * 128, ssq + l * 128, nullptr, nullptr, NNODES);
        if (l < 2) {
            mfma_gemm_kernel<false, true, false><<<gemm_grid, 256, 0, stream>>>(
                zbb, wf + (size_t)(2 * l + 1) * 16384, bB[l], hbb, gm[l], bt[l],
                ssum + l * 128, ssq + l * 128, nullptr, nullptr, NNODES);
        } else {
            mfma_gemm_kernel<false, true, true><<<gemm_grid, 256, 0, stream>>>(
                zbb, wf + (size_t)(2 * l + 1) * 16384, bB[l], nullptr, gm[l], bt[l],
                ssum + l * 128, ssq + l * 128, gptr, (float*)d_out, NNODES);
        }
        hin = hbb;
    }
}

// Round 7
// 434.079 us; speedup vs baseline: 1.5492x; 1.1650x over previous
//
#include <hip/hip_runtime.h>

#define NNODES 50000
#define NEDGES 800000
#define HD 128
#define NG 512
#define BN_EPS 1e-5f
#define GEMM_NB 391   // blocks; each handles tiles {b, b+391} of 782

typedef short bf16x8 __attribute__((ext_vector_type(8)));
typedef float floatx4 __attribute__((ext_vector_type(4)));

union U16 { uint4 u; bf16x8 h; };

__device__ __forceinline__ ushort f2bf(float f) {
    unsigned u = __float_as_uint(f);
    return (ushort)((u + 0x7fffu + ((u >> 16) & 1u)) >> 16);
}
__device__ __forceinline__ void unpack8(const uint4& u, float* f) {
    const unsigned* w = (const unsigned*)&u;
#pragma unroll
    for (int i = 0; i < 4; ++i) {
        f[2 * i]     = __uint_as_float(w[i] << 16);
        f[2 * i + 1] = __uint_as_float(w[i] & 0xffff0000u);
    }
}
__device__ __forceinline__ uint4 pack8(const float* f) {
    uint4 o;
    unsigned* w = (unsigned*)&o;
#pragma unroll
    for (int i = 0; i < 4; ++i)
        w[i] = (unsigned)f2bf(f[2 * i]) | ((unsigned)f2bf(f[2 * i + 1]) << 16);
    return o;
}

// ---------------- CSR build ----------------

__global__ void hist_kernel(const int* __restrict__ dst, int* __restrict__ cnt, int n) {
    int i = blockIdx.x * 256 + threadIdx.x;
    if (i < n) atomicAdd(&cnt[dst[i]], 1);
}

__global__ void scan1_kernel(const int* __restrict__ cnt, int* __restrict__ incl,
                             int* __restrict__ bsum, int n) {
    __shared__ int s[1024];
    int i = blockIdx.x * 1024 + threadIdx.x;
    int v = (i < n) ? cnt[i] : 0;
    s[threadIdx.x] = v;
    __syncthreads();
    for (int off = 1; off < 1024; off <<= 1) {
        int add = (threadIdx.x >= off) ? s[threadIdx.x - off] : 0;
        __syncthreads();
        s[threadIdx.x] += add;
        __syncthreads();
    }
    if (i < n) incl[i] = s[threadIdx.x];
    if (threadIdx.x == 1023) bsum[blockIdx.x] = s[1023];
}

__global__ void scan2_kernel(const int* __restrict__ bsum, int* __restrict__ boffs, int nb) {
    __shared__ int s[64];
    int v = (threadIdx.x < nb) ? bsum[threadIdx.x] : 0;
    s[threadIdx.x] = v;
    __syncthreads();
    for (int off = 1; off < 64; off <<= 1) {
        int add = (threadIdx.x >= off) ? s[threadIdx.x - off] : 0;
        __syncthreads();
        s[threadIdx.x] += add;
        __syncthreads();
    }
    if (threadIdx.x < nb) boffs[threadIdx.x] = s[threadIdx.x] - v;  // exclusive
}

__global__ void scan3_kernel(const int* __restrict__ incl, const int* __restrict__ boffs,
                             int* __restrict__ rowp, int n) {
    int i = blockIdx.x * 256 + threadIdx.x;
    if (i < n) rowp[i + 1] = incl[i] + boffs[i >> 10];
    if (i == 0) rowp[0] = 0;
}

__global__ void build_kernel(const int* __restrict__ src, const int* __restrict__ dst,
                             const int* __restrict__ rowp, int* __restrict__ fill,
                             int* __restrict__ colv, int n) {
    int i = blockIdx.x * 256 + threadIdx.x;
    if (i < n) {
        int d = dst[i];
        int pos = rowp[d] + atomicAdd(&fill[d], 1);
        colv[pos] = src[i];
    }
}

// ---------------- fp32 -> bf16 convert ----------------

__global__ void cvt_kernel(const float* __restrict__ x, ushort* __restrict__ xb, int n4) {
    int i = blockIdx.x * 256 + threadIdx.x;
    if (i < n4) {
        float4 v = ((const float4*)x)[i];
        ushort4 o;
        o.x = f2bf(v.x); o.y = f2bf(v.y); o.z = f2bf(v.z); o.w = f2bf(v.w);
        ((ushort4*)xb)[i] = o;
    }
}

// ---------------- pack weights into MFMA B-fragment order (bf16) ----------------

struct WP6 { const float* w[6]; };

__global__ void wfrag_kernel(WP6 p, ushort* __restrict__ wf) {
    const float* W = p.w[blockIdx.x];
    ushort* o = wf + (size_t)blockIdx.x * 16384;
    for (int i = threadIdx.x; i < 16384; i += 256) {
        int j = i & 7, lane = (i >> 3) & 63, kc = (i >> 9) & 3, ct = i >> 11;
        int k = kc * 32 + (lane >> 4) * 8 + j;
        int n = ct * 16 + (lane & 15);
        o[i] = f2bf(W[k * HD + n]);
    }
}

// ---------------- aggregation (bf16 rows, fp32 accumulate) ----------------

__global__ __launch_bounds__(256) void aggregate_kernel(
    const ushort* __restrict__ h, const int* __restrict__ rowp,
    const int* __restrict__ colv, ushort* __restrict__ outv, int n) {
    int node = blockIdx.x * 16 + (threadIdx.x >> 4);
    int l = threadIdx.x & 15;  // 16 lanes/node, 16B each
    if (node >= n) return;
    int beg = rowp[node], end = rowp[node + 1];
    const uint4* hp = (const uint4*)h;
    float a[8];
    uint4 sv = hp[(size_t)node * 16 + l];
    unpack8(sv, a);
    for (int j = beg; j < end; ++j) {
        uint4 v = hp[(size_t)colv[j] * 16 + l];
        float b[8];
        unpack8(v, b);
#pragma unroll
        for (int i = 0; i < 8; ++i) a[i] += b[i];
    }
    ((uint4*)outv)[(size_t)node * 16 + l] = pack8(a);
}

// ---------------- MFMA GEMM: [N,128](bf16) @ [128,128](bf16 frags) + bias ----------
// 391 blocks x 256 threads; block b computes tiles b and b+391 (64 rows each).
// B-fragments (32 KB) staged in LDS once per block. A prefetched one tile ahead.
// Stats accumulate in registers across tiles -> one 8-way-split atomic set/block.

template <bool STATS, bool PRE_BN, bool READOUT>
__global__ __launch_bounds__(256, 3) void mfma_gemm_kernel(
    const ushort* __restrict__ A, const ushort* __restrict__ Wf,
    const float* __restrict__ bias, ushort* __restrict__ out,
    const float* __restrict__ gamma, const float* __restrict__ beta,
    float* __restrict__ ssum_p, float* __restrict__ ssq_p,
    const int* __restrict__ gptr, float* __restrict__ gout, int nrows) {
    __shared__ ushort bs[16384];     // 32 KB B-fragments (persistent)
    __shared__ ushort cbuf[8192];    // 16 KB C tile
    __shared__ float reds[4][HD];
    __shared__ float redq[4][HD];
    __shared__ float sca[HD];
    __shared__ float shf[HD];
    const int t = threadIdx.x;
    const int wave = t >> 6, lane = t & 63;
    const int quad = lane >> 4, l16 = lane & 15;

    // stage B into LDS
    {
        const uint4* g = (const uint4*)Wf;
        uint4 v[8];
#pragma unroll
        for (int i = 0; i < 8; ++i) v[i] = g[i * 256 + t];
        uint4* s = (uint4*)bs;
#pragma unroll
        for (int i = 0; i < 8; ++i) s[i * 256 + t] = v[i];
    }

    // inline BN finalize from 8-way-split raw stats (stream-ordered complete)
    if (PRE_BN && t < HD) {
        float s = 0.f, q = 0.f;
#pragma unroll
        for (int i = 0; i < 8; ++i) { s += ssum_p[i * HD + t]; q += ssq_p[i * HD + t]; }
        float mean = s / (float)nrows;
        float var = q / (float)nrows - mean * mean;
        float rstd = rsqrtf(var + BN_EPS);
        float sc = gamma[t] * rstd;
        sca[t] = sc;
        shf[t] = beta[t] - mean * sc;
    }

    // A loads for tile 0: issue before the barrier
    uint4 a_cur[4];
    {
        int rowA = blockIdx.x * 64 + wave * 16 + l16;
        bool ok = rowA < nrows;
        const ushort* ap = A + (size_t)rowA * HD + quad * 8;
#pragma unroll
        for (int kc = 0; kc < 4; ++kc)
            a_cur[kc] = ok ? *(const uint4*)(ap + kc * 32) : make_uint4(0, 0, 0, 0);
    }

    __syncthreads();

    float s_acc[8], q_acc[8];
#pragma unroll
    for (int i = 0; i < 8; ++i) { s_acc[i] = 0.f; q_acc[i] = 0.f; }

    const uint4* B4 = (const uint4*)bs;
    floatx4 zf = {0.f, 0.f, 0.f, 0.f};

#pragma unroll
    for (int j = 0; j < 2; ++j) {
        const int tile = blockIdx.x + j * GEMM_NB;
        const int row0 = tile * 64;

        uint4 a_use[4];
#pragma unroll
        for (int kc = 0; kc < 4; ++kc) a_use[kc] = a_cur[kc];

        // prefetch next tile's A
        if (j == 0) {
            int rowA = (blockIdx.x + GEMM_NB) * 64 + wave * 16 + l16;
            bool ok = rowA < nrows;
            const ushort* ap = A + (size_t)rowA * HD + quad * 8;
#pragma unroll
            for (int kc = 0; kc < 4; ++kc)
                a_cur[kc] = ok ? *(const uint4*)(ap + kc * 32) : make_uint4(0, 0, 0, 0);
        }

        if (row0 < nrows) {
            floatx4 acc[8];
#pragma unroll
            for (int i = 0; i < 8; ++i) acc[i] = zf;

#pragma unroll
            for (int kc = 0; kc < 4; ++kc) {
                U16 au;
                au.u = a_use[kc];
                if (PRE_BN) {
                    float f[8];
                    unpack8(au.u, f);
                    int kb = kc * 32 + quad * 8;
                    float4 s0 = ((const float4*)(sca + kb))[0];
                    float4 s1 = ((const float4*)(sca + kb))[1];
                    float4 h0 = ((const float4*)(shf + kb))[0];
                    float4 h1 = ((const float4*)(shf + kb))[1];
                    f[0] = fmaxf(fmaf(f[0], s0.x, h0.x), 0.f);
                    f[1] = fmaxf(fmaf(f[1], s0.y, h0.y), 0.f);
                    f[2] = fmaxf(fmaf(f[2], s0.z, h0.z), 0.f);
                    f[3] = fmaxf(fmaf(f[3], s0.w, h0.w), 0.f);
                    f[4] = fmaxf(fmaf(f[4], s1.x, h1.x), 0.f);
                    f[5] = fmaxf(fmaf(f[5], s1.y, h1.y), 0.f);
                    f[6] = fmaxf(fmaf(f[6], s1.z, h1.z), 0.f);
                    f[7] = fmaxf(fmaf(f[7], s1.w, h1.w), 0.f);
                    au.u = pack8(f);
                }
#pragma unroll
                for (int ct = 0; ct < 8; ++ct) {
                    U16 bu;
                    bu.u = B4[(ct * 4 + kc) * 64 + lane];
                    acc[ct] = __builtin_amdgcn_mfma_f32_16x16x32_bf16(au.h, bu.h, acc[ct], 0, 0, 0);
                }
            }

            // C/D layout: col = ct*16 + l16, row = row0 + wave*16 + quad*4 + reg
            const int r_base = row0 + wave * 16 + quad * 4;

            if (READOUT) {
                int segr[4] = {-1, -1, -1, -1};
                if (r_base < nrows) {
                    int lo = 0, hi = NG - 1;
                    while (lo < hi) {
                        int mid = (lo + hi) >> 1;
                        if (r_base >= gptr[mid + 1]) lo = mid + 1; else hi = mid;
                    }
                    int sg = lo;
#pragma unroll
                    for (int reg = 0; reg < 4; ++reg) {
                        int rw = r_base + reg;
                        if (rw < nrows) {
                            while (rw >= gptr[sg + 1]) ++sg;
                            segr[reg] = sg;
                        }
                    }
                }
#pragma unroll
                for (int ct = 0; ct < 8; ++ct) {
                    int col = ct * 16 + l16;
                    float b = bias[col];
                    float run = 0.f;
                    int cur = segr[0];
#pragma unroll
                    for (int reg = 0; reg < 4; ++reg) {
                        if (segr[reg] != cur) {
                            if (cur >= 0 && run != 0.f) atomicAdd(&gout[cur * HD + col], run);
                            run = 0.f;
                            cur = segr[reg];
                        }
                        if (cur >= 0) run += fmaxf(acc[ct][reg] + b, 0.f);
                    }
                    if (cur >= 0 && run != 0.f) atomicAdd(&gout[cur * HD + col], run);
                }
            } else {
                const int lrow = wave * 16 + quad * 4;
#pragma unroll
                for (int ct = 0; ct < 8; ++ct) {
                    int col = ct * 16 + l16;
                    float b = bias[ct * 16 + l16];
#pragma unroll
                    for (int reg = 0; reg < 4; ++reg) {
                        float v = acc[ct][reg] + b;
                        if (!STATS) v = fmaxf(v, 0.f);  // GEMM-B: relu; GEMM-A: raw
                        cbuf[(lrow + reg) * HD + col] = f2bf(v);
                        if (STATS && (r_base + reg) < nrows) {
                            s_acc[ct] += v;
                            q_acc[ct] += v * v;
                        }
                    }
                }
                __syncthreads();  // C tile complete
                const uint4* c4 = (const uint4*)cbuf;
                uint4* o4 = (uint4*)out;
#pragma unroll
                for (int i = 0; i < 4; ++i) {
                    int f = t * 4 + i;
                    int row = f >> 4;
                    if (row0 + row < nrows) o4[(size_t)(row0 + row) * 16 + (f & 15)] = c4[f];
                }
                __syncthreads();  // stores' reads done before next tile reuses cbuf
            }
        }
    }

    if (STATS) {
#pragma unroll
        for (int ct = 0; ct < 8; ++ct) {
            float s = s_acc[ct], q = q_acc[ct];
            s += __shfl_xor(s, 16); s += __shfl_xor(s, 32);
            q += __shfl_xor(q, 16); q += __shfl_xor(q, 32);
            if (quad == 0) { reds[wave][ct * 16 + l16] = s; redq[wave][ct * 16 + l16] = q; }
        }
        __syncthreads();
        int slot = (blockIdx.x & 7) * HD;
        if (t < HD) {
            atomicAdd(&ssum_p[slot + t], reds[0][t] + reds[1][t] + reds[2][t] + reds[3][t]);
        } else if (t < 2 * HD) {
            int c = t - HD;
            atomicAdd(&ssq_p[slot + c], redq[0][c] + redq[1][c] + redq[2][c] + redq[3][c]);
        }
    }
}

// ---------------- launch ----------------

extern "C" void kernel_launch(void* const* d_in, const int* in_sizes, int n_in,
                              void* d_out, int out_size, void* d_ws, size_t ws_size,
                              hipStream_t stream) {
    const float* x = (const float*)d_in[0];
    const int* esrc = (const int*)d_in[1];
    const int* edst = (const int*)d_in[2];
    const int* gptr = (const int*)d_in[3];
    const float* wA[3] = {(const float*)d_in[4], (const float*)d_in[10], (const float*)d_in[16]};
    const float* bA[3] = {(const float*)d_in[5], (const float*)d_in[11], (const float*)d_in[17]};
    const float* gm[3] = {(const float*)d_in[6], (const float*)d_in[12], (const float*)d_in[18]};
    const float* bt[3] = {(const float*)d_in[7], (const float*)d_in[13], (const float*)d_in[19]};
    const float* wB[3] = {(const float*)d_in[8], (const float*)d_in[14], (const float*)d_in[20]};
    const float* bB[3] = {(const float*)d_in[9], (const float*)d_in[15], (const float*)d_in[21]};

    char* w = (char*)d_ws;
    ushort* xb   = (ushort*)w; w += (size_t)NNODES * HD * 2;  // 12.8 MB
    ushort* tmpb = (ushort*)w; w += (size_t)NNODES * HD * 2;
    ushort* zbb  = (ushort*)w; w += (size_t)NNODES * HD * 2;
    ushort* hbb  = (ushort*)w; w += (size_t)NNODES * HD * 2;
    ushort* wf   = (ushort*)w; w += (size_t)6 * 16384 * 2;    // 192 KB
    int* colv  = (int*)w;   w += (size_t)NEDGES * 4;
    int* incl  = (int*)w;   w += (size_t)NNODES * 4;
    int* rowp  = (int*)w;   w += ((size_t)(NNODES + 1) * 4 + 15) & ~(size_t)15;
    int* bsum  = (int*)w;   w += 64 * 4;
    int* boffs = (int*)w;   w += 64 * 4;
    // ---- zero region ----
    char* zero_base = w;
    int* cnt   = (int*)w;   w += (size_t)NNODES * 4;
    int* fill  = (int*)w;   w += (size_t)NNODES * 4;
    float* ssum_p = (float*)w; w += 3 * 8 * 128 * 4;
    float* ssq_p  = (float*)w; w += 3 * 8 * 128 * 4;
    size_t zero_bytes = (size_t)(w - zero_base);

    hipMemsetAsync(zero_base, 0, zero_bytes, stream);
    hipMemsetAsync(d_out, 0, (size_t)NG * HD * 4, stream);

    // CSR by destination
    hist_kernel<<<(NEDGES + 255) / 256, 256, 0, stream>>>(edst, cnt, NEDGES);
    int nsb = (NNODES + 1023) / 1024;  // 49
    scan1_kernel<<<nsb, 1024, 0, stream>>>(cnt, incl, bsum, NNODES);
    scan2_kernel<<<1, 64, 0, stream>>>(bsum, boffs, nsb);
    scan3_kernel<<<(NNODES + 255) / 256, 256, 0, stream>>>(incl, boffs, rowp, NNODES);
    build_kernel<<<(NEDGES + 255) / 256, 256, 0, stream>>>(esrc, edst, rowp, fill, colv, NEDGES);

    cvt_kernel<<<(NNODES * HD / 4 + 255) / 256, 256, 0, stream>>>(x, xb, NNODES * HD / 4);
    WP6 wp;
    wp.w[0] = wA[0]; wp.w[1] = wB[0]; wp.w[2] = wA[1];
    wp.w[3] = wB[1]; wp.w[4] = wA[2]; wp.w[5] = wB[2];
    wfrag_kernel<<<6, 256, 0, stream>>>(wp, wf);

    const int agg_grid = (NNODES + 15) / 16;   // 3125
    const ushort* hin = xb;
    for (int l = 0; l < 3; ++l) {
        aggregate_kernel<<<agg_grid, 256, 0, stream>>>(hin, rowp, colv, tmpb, NNODES);
        mfma_gemm_kernel<true, false, false><<<GEMM_NB, 256, 0, stream>>>(
            tmpb, wf + (size_t)(2 * l) * 16384, bA[l], zbb, nullptr, nullptr,
            ssum_p + l * 1024, ssq_p + l * 1024, nullptr, nullptr, NNODES);
        if (l < 2) {
            mfma_gemm_kernel<false, true, false><<<GEMM_NB, 256, 0, stream>>>(
                zbb, wf + (size_t)(2 * l + 1) * 16384, bB[l], hbb, gm[l], bt[l],
                ssum_p + l * 1024, ssq_p + l * 1024, nullptr, nullptr, NNODES);
        } else {
            mfma_gemm_kernel<false, true, true><<<GEMM_NB, 256, 0, stream>>>(
                zbb, wf + (size_t)(2 * l + 1) * 16384, bB[l], nullptr, gm[l], bt[l],
                ssum_p + l * 1024, ssq_p + l * 1024, gptr, (float*)d_out, NNODES);
        }
        hin = hbb;
    }
}